// Round 1
// baseline (962.146 us; speedup 1.0000x reference)
//
#include <hip/hip_runtime.h>
#include <cstdint>

namespace {

constexpr int BS   = 2048;
constexpr int DIM  = 256;
constexpr int K    = 3000;
constexpr int QL   = 3840;
constexpr int NTOT = QL + BS;      // 5888
constexpr int N2   = 2 * BS;       // 4096
constexpr float TEMP = 0.2f;
constexpr float EPS  = 0.05f;
constexpr int CHUNK = 128;

// ws layout (float indices)
constexpr size_t OFF_Q0Q   = 0;                        // QL*K
constexpr size_t OFF_U     = (size_t)QL * K;           // K
constexpr size_t OFF_S     = OFF_U + K;                // K
constexpr size_t OFF_V     = OFF_S + K;                // NTOT
constexpr size_t OFF_OUTC  = ((OFF_V + NTOT + 15) / 16) * 16; // N2*DIM
constexpr size_t OFF_ACC   = OFF_OUTC + (size_t)N2 * DIM;     // 8
constexpr size_t OFF_HQ    = OFF_ACC + 8;              // N2 ints
constexpr size_t OFF_NQ    = OFF_HQ + N2;              // N2*6 ints

__device__ __forceinline__ float wave_sum(float v) {
#pragma unroll
  for (int off = 32; off > 0; off >>= 1) v += __shfl_down(v, off, 64);
  return v;
}
__device__ __forceinline__ float wave_max(float v) {
#pragma unroll
  for (int off = 32; off > 0; off >>= 1) v = fmaxf(v, __shfl_down(v, off, 64));
  return v;
}
__device__ __forceinline__ unsigned long long wave_maxu64(unsigned long long v) {
#pragma unroll
  for (int off = 32; off > 0; off >>= 1) {
    unsigned long long o = __shfl_down(v, off, 64);
    v = (o > v) ? o : v;
  }
  return v;
}
// monotone float->uint map (ascending float order == ascending uint order)
__device__ __forceinline__ unsigned int fmono(float f) {
  unsigned int u = __float_as_uint(f);
  return (u & 0x80000000u) ? ~u : (u | 0x80000000u);
}

// ---------------- GEMM: Q0q[n][k] = exp((queue_crop[n] . proto[k]) / EPS) ----------------
__global__ __launch_bounds__(256) void k_gemm_exp(
    const float* __restrict__ A,   // [QL][DIM]
    const float* __restrict__ B,   // [K][DIM]
    float* __restrict__ Q0q) {     // [QL][K]
  __shared__ float As[64][65];   // [d][m]
  __shared__ float Bs[64][65];   // [d][n(k)]
  const int bk0 = blockIdx.x * 64;   // k tile
  const int bn0 = blockIdx.y * 64;   // row tile
  const int tid = threadIdx.x;
  const int tx = tid & 15, ty = tid >> 4;
  const int lr = tid >> 4;          // 0..15
  const int lc = (tid & 15) * 4;    // 0..60
  float acc[4][4] = {};
  for (int d0 = 0; d0 < DIM; d0 += 64) {
#pragma unroll
    for (int s = 0; s < 4; ++s) {
      int n = bn0 + lr + 16 * s;
      const float4 va = *reinterpret_cast<const float4*>(&A[(size_t)n * DIM + d0 + lc]);
      As[lc + 0][lr + 16 * s] = va.x;
      As[lc + 1][lr + 16 * s] = va.y;
      As[lc + 2][lr + 16 * s] = va.z;
      As[lc + 3][lr + 16 * s] = va.w;
      int kg = bk0 + lr + 16 * s;
      float4 vb = make_float4(0.f, 0.f, 0.f, 0.f);
      if (kg < K) vb = *reinterpret_cast<const float4*>(&B[(size_t)kg * DIM + d0 + lc]);
      Bs[lc + 0][lr + 16 * s] = vb.x;
      Bs[lc + 1][lr + 16 * s] = vb.y;
      Bs[lc + 2][lr + 16 * s] = vb.z;
      Bs[lc + 3][lr + 16 * s] = vb.w;
    }
    __syncthreads();
#pragma unroll 8
    for (int dd = 0; dd < 64; ++dd) {
      float a[4], b[4];
#pragma unroll
      for (int i = 0; i < 4; ++i) a[i] = As[dd][ty * 4 + i];
#pragma unroll
      for (int j = 0; j < 4; ++j) b[j] = Bs[dd][tx * 4 + j];
#pragma unroll
      for (int i = 0; i < 4; ++i)
#pragma unroll
        for (int j = 0; j < 4; ++j) acc[i][j] += a[i] * b[j];
    }
    __syncthreads();
  }
#pragma unroll
  for (int i = 0; i < 4; ++i) {
    int n = bn0 + ty * 4 + i;
#pragma unroll
    for (int j = 0; j < 4; ++j) {
      int kg = bk0 + tx * 4 + j;
      if (kg < K) Q0q[(size_t)n * K + kg] = expf(acc[i][j] / EPS);
    }
  }
}

__global__ void k_init_v(float* __restrict__ v) {
  int n = blockIdx.x * 256 + threadIdx.x;
  if (n < NTOT) v[n] = 1.0f;
}

// S[k] += sum_n data[n][k] * v[n]   (data = Q0q rows or exp(output) rows)
__global__ __launch_bounds__(256) void k_colsum(
    const float* __restrict__ Q0q, const float* __restrict__ outCrop,
    const float* __restrict__ v, float* __restrict__ S) {
  int k = blockIdx.x * 256 + threadIdx.x;
  int n0 = blockIdx.y * CHUNK;
  if (k >= K) return;
  float acc = 0.f;
  for (int nn = 0; nn < CHUNK; ++nn) {
    int n = n0 + nn;
    float val = (n < QL) ? Q0q[(size_t)n * K + k]
                         : expf(outCrop[(size_t)(n - QL) * K + k] / EPS);
    acc += val * v[n];
  }
  atomicAdd(&S[k], acc);
}

__global__ void k_update_u(const float* __restrict__ S, float* __restrict__ u) {
  int k = blockIdx.x * 256 + threadIdx.x;
  if (k < K) u[k] = 1.0f / ((float)K * S[k]);
}

// v[n] = 1 / (NTOT * sum_k data[n][k]*u[k])
__global__ __launch_bounds__(256) void k_rowpass(
    const float* __restrict__ Q0q, const float* __restrict__ outCrop,
    const float* __restrict__ u, float* __restrict__ v) {
  __shared__ float s4[4];
  int n = blockIdx.x;
  float acc = 0.f;
  if (n < QL) {
    const float* row = &Q0q[(size_t)n * K];
    for (int k = threadIdx.x; k < K; k += 256) acc += row[k] * u[k];
  } else {
    const float* row = &outCrop[(size_t)(n - QL) * K];
    for (int k = threadIdx.x; k < K; k += 256) acc += expf(row[k] / EPS) * u[k];
  }
  acc = wave_sum(acc);
  if ((threadIdx.x & 63) == 0) s4[threadIdx.x >> 6] = acc;
  __syncthreads();
  if (threadIdx.x == 0) v[n] = 1.0f / ((float)NTOT * (s4[0] + s4[1] + s4[2] + s4[3]));
}

// per sample row: hard_q (argmax), neg_q (argsort[2:8]) and crop-1 cc term
__global__ __launch_bounds__(256) void k_stats(
    const float* __restrict__ outputAll, const float* __restrict__ u,
    const float* __restrict__ v, int crop,
    int* __restrict__ hardq, int* __restrict__ negq, float* __restrict__ accum) {
  __shared__ float skey[K];                  // 12 KB: key[k] = exp(out/EPS)*u[k]
  __shared__ unsigned long long ml[256][8];  // 16 KB merge lists
  __shared__ unsigned long long sm4[4];
  __shared__ float s4[4];
  __shared__ float r3[3][4];
  const int tid = threadIdx.x;
  const int j = blockIdx.x;
  const float* orow = outputAll + (size_t)(crop * BS + j) * K;

  for (int k = tid; k < K; k += 256) skey[k] = expf(orow[k] / EPS) * u[k];
  __syncthreads();

  // argmax, first-occurrence semantics: maximize (key, ~k)
  unsigned long long am = 0ull;
  for (int k = tid; k < K; k += 256) {
    unsigned long long p = ((unsigned long long)fmono(skey[k]) << 32) | (unsigned int)(~k);
    am = (p > am) ? p : am;
  }
  am = wave_maxu64(am);
  if ((tid & 63) == 0) sm4[tid >> 6] = am;

  // bottom-8 (stable ascending argsort semantics: minimize (key, k))
  unsigned long long best[8];
#pragma unroll
  for (int t = 0; t < 8; ++t) best[t] = ~0ull;
  for (int k = tid; k < K; k += 256) {
    unsigned long long p = ((unsigned long long)fmono(skey[k]) << 32) | (unsigned int)k;
    if (p < best[7]) {
      best[7] = p;
#pragma unroll
      for (int t = 7; t > 0; --t)
        if (best[t] < best[t - 1]) {
          unsigned long long tmp = best[t]; best[t] = best[t - 1]; best[t - 1] = tmp;
        }
    }
  }
#pragma unroll
  for (int t = 0; t < 8; ++t) ml[tid][t] = best[t];
  __syncthreads();
  for (int off = 128; off >= 1; off >>= 1) {
    if (tid < off) {
      unsigned long long a[8], b[8], o[8];
#pragma unroll
      for (int t = 0; t < 8; ++t) { a[t] = ml[tid][t]; b[t] = ml[tid + off][t]; }
      int ia = 0, ib = 0;
#pragma unroll
      for (int t = 0; t < 8; ++t) o[t] = (a[ia] <= b[ib]) ? a[ia++] : b[ib++];
#pragma unroll
      for (int t = 0; t < 8; ++t) ml[tid][t] = o[t];
    }
    __syncthreads();
  }
  if (tid == 0) {
    unsigned long long amx = sm4[0];
#pragma unroll
    for (int t = 1; t < 4; ++t) amx = (sm4[t] > amx) ? sm4[t] : amx;
    hardq[crop * BS + j] = (int)(~(unsigned int)(amx & 0xffffffffull));
#pragma unroll
    for (int r = 0; r < 6; ++r)
      negq[(size_t)(crop * BS + j) * 6 + r] = (int)(unsigned int)(ml[0][2 + r] & 0xffffffffull);
  }

  if (crop == 1) {
    // cc term: sum_k q[n,k] * log_softmax(output[0:BS]/TEMP)[j,k]
    const float* xrow = outputAll + (size_t)j * K;
    float mx = -3.4e38f;
    for (int k = tid; k < K; k += 256) mx = fmaxf(mx, xrow[k]);
    mx = wave_max(mx);
    if ((tid & 63) == 0) s4[tid >> 6] = mx;
    __syncthreads();
    mx = fmaxf(fmaxf(s4[0], s4[1]), fmaxf(s4[2], s4[3]));
    float se = 0.f, sk = 0.f, skx = 0.f;
    for (int k = tid; k < K; k += 256) {
      float x = xrow[k];
      se += expf((x - mx) / TEMP);
      float kv = skey[k];
      sk += kv;
      skx += kv * x;
    }
    se = wave_sum(se); sk = wave_sum(sk); skx = wave_sum(skx);
    if ((tid & 63) == 0) { int w = tid >> 6; r3[0][w] = se; r3[1][w] = sk; r3[2][w] = skx; }
    __syncthreads();
    if (tid == 0) {
      float SE  = r3[0][0] + r3[0][1] + r3[0][2] + r3[0][3];
      float SK  = r3[1][0] + r3[1][1] + r3[1][2] + r3[1][3];
      float SKX = r3[2][0] + r3[2][1] + r3[2][2] + r3[2][3];
      float bv  = (float)NTOT * v[QL + j];
      float sq  = bv * SK;                 // sum_k q
      float sqx = bv * SKX / TEMP;         // sum_k q*x
      float lse = mx / TEMP + logf(SE);
      atomicAdd(&accum[2], sqx - lse * sq);
    }
  }
}

__global__ __launch_bounds__(256) void k_normalize(
    const float* __restrict__ emb, float* __restrict__ outc) {
  __shared__ float s4[4];
  __shared__ float nrm;
  int r = blockIdx.x;
  int src = (r < BS) ? (BS + r) : (r - BS);
  float z = emb[(size_t)src * DIM + threadIdx.x] / TEMP;
  float ss = wave_sum(z * z);
  if ((threadIdx.x & 63) == 0) s4[threadIdx.x >> 6] = ss;
  __syncthreads();
  if (threadIdx.x == 0) nrm = sqrtf(s4[0] + s4[1] + s4[2] + s4[3]);
  __syncthreads();
  outc[(size_t)r * DIM + threadIdx.x] = z / nrm;
}

__global__ __launch_bounds__(256) void k_pos(
    const float* __restrict__ outc, float* __restrict__ accum) {
  int wid = threadIdx.x >> 6, lane = threadIdx.x & 63;
  int j = blockIdx.x * 4 + wid;
  const float4 a = reinterpret_cast<const float4*>(outc + (size_t)j * DIM)[lane];
  const float4 b = reinterpret_cast<const float4*>(outc + (size_t)(BS + j) * DIM)[lane];
  float d = a.x * b.x + a.y * b.y + a.z * b.z + a.w * b.w;
  d = wave_sum(d);
  if (lane == 0) atomicAdd(&accum[1], d);
}

__global__ __launch_bounds__(256) void k_denom(
    const float* __restrict__ outc, const int* __restrict__ hardq,
    const int* __restrict__ negq, float* __restrict__ accum) {
  __shared__ int shq[N2];       // 16 KB
  __shared__ float4 srow[64];   // row i
  __shared__ float s4[4];
  const int i = blockIdx.x;
  const int tid = threadIdx.x;
  for (int t = tid; t < N2; t += 256) shq[t] = hardq[t];
  if (tid < 64) srow[tid] = reinterpret_cast<const float4*>(outc + (size_t)i * DIM)[tid];
  int q0 = negq[i * 6 + 0], q1 = negq[i * 6 + 1], q2 = negq[i * 6 + 2],
      q3 = negq[i * 6 + 3], q4 = negq[i * 6 + 4], q5 = negq[i * 6 + 5];
  __syncthreads();
  float acc = 0.f;
  for (int jj = tid; jj < N2; jj += 256) {
    if (jj == i) continue;
    int h = shq[jj];
    if (h == q0 || h == q1 || h == q2 || h == q3 || h == q4 || h == q5) {
      const float4* rj = reinterpret_cast<const float4*>(outc + (size_t)jj * DIM);
      float ds = 0.f;
#pragma unroll 8
      for (int d4 = 0; d4 < 64; ++d4) {
        float4 a = srow[d4]; float4 b = rj[d4];
        ds += a.x * b.x + a.y * b.y + a.z * b.z + a.w * b.w;
      }
      acc += expf(ds / TEMP);
    }
  }
  acc = wave_sum(acc);
  __syncthreads();
  if ((tid & 63) == 0) s4[tid >> 6] = acc;
  __syncthreads();
  if (tid == 0) atomicAdd(&accum[0], s4[0] + s4[1] + s4[2] + s4[3]);
}

__global__ void k_final(const float* __restrict__ accum, float* __restrict__ out) {
  float denom  = accum[0];
  float possum = accum[1];
  float ccsum  = accum[2];
  float contrast = logf(denom) - possum / ((float)BS * TEMP);
  float cc_loss  = -ccsum / (float)BS;
  out[0] = contrast + 6.0f * cc_loss;
}

}  // namespace

extern "C" void kernel_launch(void* const* d_in, const int* in_sizes, int n_in,
                              void* d_out, int out_size, void* d_ws, size_t ws_size,
                              hipStream_t stream) {
  const float* queue  = (const float*)d_in[3];  // [2][QL][DIM]
  const float* proto  = (const float*)d_in[4];  // [K][DIM]
  const float* output = (const float*)d_in[5];  // [2*BS][K]
  const float* emb    = (const float*)d_in[6];  // [2*BS][DIM]
  float* ws = (float*)d_ws;
  float* Q0q   = ws + OFF_Q0Q;
  float* u     = ws + OFF_U;
  float* S     = ws + OFF_S;
  float* v     = ws + OFF_V;
  float* outc  = ws + OFF_OUTC;
  float* accum = ws + OFF_ACC;
  int* hardq = (int*)(ws + OFF_HQ);
  int* negq  = (int*)(ws + OFF_NQ);
  float* out = (float*)d_out;

  hipMemsetAsync(accum, 0, 8 * sizeof(float), stream);

  for (int crop = 0; crop < 2; ++crop) {
    const float* qcrop = queue + (size_t)crop * QL * DIM;
    const float* ocrop = output + (size_t)crop * BS * K;
    k_gemm_exp<<<dim3((K + 63) / 64, QL / 64), 256, 0, stream>>>(qcrop, proto, Q0q);
    k_init_v<<<(NTOT + 255) / 256, 256, 0, stream>>>(v);
    for (int it = 0; it < 3; ++it) {
      hipMemsetAsync(S, 0, K * sizeof(float), stream);
      k_colsum<<<dim3((K + 255) / 256, NTOT / CHUNK), 256, 0, stream>>>(Q0q, ocrop, v, S);
      k_update_u<<<(K + 255) / 256, 256, 0, stream>>>(S, u);
      k_rowpass<<<NTOT, 256, 0, stream>>>(Q0q, ocrop, u, v);
    }
    k_stats<<<BS, 256, 0, stream>>>(output, u, v, crop, hardq, negq, accum);
  }

  k_normalize<<<N2, 256, 0, stream>>>(emb, outc);
  k_pos<<<BS / 4, 256, 0, stream>>>(outc, accum);
  k_denom<<<N2, 256, 0, stream>>>(outc, hardq, negq, accum);
  k_final<<<1, 1, 0, stream>>>(accum, out);
}

// Round 2
// 594.601 us; speedup vs baseline: 1.6181x; 1.6181x over previous
//
#include <hip/hip_runtime.h>
#include <hip/hip_bf16.h>
#include <cstdint>

namespace {

constexpr int BS   = 2048;
constexpr int DIM  = 256;
constexpr int K    = 3000;
constexpr int K4   = K / 4;        // 750
constexpr int QL   = 3840;
constexpr int NTOT = QL + BS;      // 5888
constexpr int N2   = 2 * BS;       // 4096
constexpr float TEMP = 0.2f;
constexpr float EPS  = 0.05f;
constexpr float INV_EPS = 20.0f;
constexpr int CHUNK = 32;

// ws layout (float indices)
constexpr size_t OFF_Q0Q  = 0;                          // QL*K
constexpr size_t OFF_U    = (size_t)QL * K;             // K
constexpr size_t OFF_S    = OFF_U + K;                  // K
constexpr size_t OFF_V    = OFF_S + K;                  // NTOT
constexpr size_t OFF_ACC  = OFF_V + NTOT;               // 8
constexpr size_t OFF_HQ   = OFF_ACC + 8;                // N2 ints
constexpr size_t OFF_NQ   = OFF_HQ + N2;                // N2*6 ints
constexpr size_t OFF_CVT  = ((OFF_NQ + (size_t)N2 * 6 + 3) / 4) * 4;
constexpr size_t CVT_ELEM = (size_t)(2 * QL + K) * DIM; // ushort count
constexpr size_t CVT_FL   = CVT_ELEM / 2;               // float-slots per array
constexpr size_t OFF_CVT_HI = OFF_CVT;
constexpr size_t OFF_CVT_LO = OFF_CVT_HI + CVT_FL;
constexpr size_t OFF_OUTC   = OFF_CVT_HI;               // reuse after GEMMs

using bf16x8 = __attribute__((ext_vector_type(8))) short;
using f32x4  = __attribute__((ext_vector_type(4))) float;

__device__ __forceinline__ float wave_sum(float v) {
#pragma unroll
  for (int off = 32; off > 0; off >>= 1) v += __shfl_down(v, off, 64);
  return v;
}
__device__ __forceinline__ float wave_max(float v) {
#pragma unroll
  for (int off = 32; off > 0; off >>= 1) v = fmaxf(v, __shfl_down(v, off, 64));
  return v;
}
__device__ __forceinline__ unsigned long long wave_maxu64(unsigned long long v) {
#pragma unroll
  for (int off = 32; off > 0; off >>= 1) {
    unsigned long long o = __shfl_down(v, off, 64);
    v = (o > v) ? o : v;
  }
  return v;
}
__device__ __forceinline__ unsigned int fmono(float f) {
  unsigned int u = __float_as_uint(f);
  return (u & 0x80000000u) ? ~u : (u | 0x80000000u);
}

// -------- split f32 -> (hi, lo) bf16 --------
__global__ __launch_bounds__(256) void k_convert(
    const float* __restrict__ x, ushort* __restrict__ hi, ushort* __restrict__ lo, int n4) {
  int i = blockIdx.x * 256 + threadIdx.x;
  if (i >= n4) return;
  float4 v = reinterpret_cast<const float4*>(x)[i];
  ushort4 h, l;
  {
    __hip_bfloat16 b = __float2bfloat16(v.x);
    h.x = *reinterpret_cast<ushort*>(&b);
    __hip_bfloat16 c = __float2bfloat16(v.x - __bfloat162float(b));
    l.x = *reinterpret_cast<ushort*>(&c);
  }
  {
    __hip_bfloat16 b = __float2bfloat16(v.y);
    h.y = *reinterpret_cast<ushort*>(&b);
    __hip_bfloat16 c = __float2bfloat16(v.y - __bfloat162float(b));
    l.y = *reinterpret_cast<ushort*>(&c);
  }
  {
    __hip_bfloat16 b = __float2bfloat16(v.z);
    h.z = *reinterpret_cast<ushort*>(&b);
    __hip_bfloat16 c = __float2bfloat16(v.z - __bfloat162float(b));
    l.z = *reinterpret_cast<ushort*>(&c);
  }
  {
    __hip_bfloat16 b = __float2bfloat16(v.w);
    h.w = *reinterpret_cast<ushort*>(&b);
    __hip_bfloat16 c = __float2bfloat16(v.w - __bfloat162float(b));
    l.w = *reinterpret_cast<ushort*>(&c);
  }
  reinterpret_cast<ushort4*>(hi)[i] = h;
  reinterpret_cast<ushort4*>(lo)[i] = l;
}

// -------- MFMA GEMM: Q0q[m][n] = exp(dot(A[m],B[n]) / EPS); S[n] += colsum --------
__global__ __launch_bounds__(256) void k_gemm_split(
    const ushort* __restrict__ Ahi_g, const ushort* __restrict__ Alo_g,  // [3840][256]
    const ushort* __restrict__ Bhi_g, const ushort* __restrict__ Blo_g,  // [3000][256]
    float* __restrict__ Q0q, float* __restrict__ S) {
  __shared__ ushort Ah[128][40], Al[128][40], Bh[128][40], Bl[128][40];
  const int tid  = threadIdx.x;
  const int bn0  = blockIdx.x * 128;  // class dim
  const int bm0  = blockIdx.y * 128;  // queue row
  const int wid  = tid >> 6, lane = tid & 63;
  const int wm0  = (wid >> 1) * 64, wn0 = (wid & 1) * 64;
  const int ln15 = lane & 15, lq = lane >> 4;
  const int lr   = tid >> 2;          // 0..63
  const int lc   = (tid & 3) * 8;     // 0,8,16,24

  f32x4 acc[4][4] = {};

  for (int kk = 0; kk < DIM; kk += 32) {
#pragma unroll
    for (int p = 0; p < 2; ++p) {
      int row = p * 64 + lr;
      size_t ga = (size_t)(bm0 + row) * DIM + kk + lc;
      int brow = bn0 + row; if (brow >= K) brow = K - 1;
      size_t gb = (size_t)brow * DIM + kk + lc;
      *reinterpret_cast<bf16x8*>(&Ah[row][lc]) = *reinterpret_cast<const bf16x8*>(&Ahi_g[ga]);
      *reinterpret_cast<bf16x8*>(&Al[row][lc]) = *reinterpret_cast<const bf16x8*>(&Alo_g[ga]);
      *reinterpret_cast<bf16x8*>(&Bh[row][lc]) = *reinterpret_cast<const bf16x8*>(&Bhi_g[gb]);
      *reinterpret_cast<bf16x8*>(&Bl[row][lc]) = *reinterpret_cast<const bf16x8*>(&Blo_g[gb]);
    }
    __syncthreads();
    bf16x8 ah[4], al[4], bh[4], bl[4];
#pragma unroll
    for (int i = 0; i < 4; ++i) {
      ah[i] = *reinterpret_cast<const bf16x8*>(&Ah[wm0 + i * 16 + ln15][lq * 8]);
      al[i] = *reinterpret_cast<const bf16x8*>(&Al[wm0 + i * 16 + ln15][lq * 8]);
      bh[i] = *reinterpret_cast<const bf16x8*>(&Bh[wn0 + i * 16 + ln15][lq * 8]);
      bl[i] = *reinterpret_cast<const bf16x8*>(&Bl[wn0 + i * 16 + ln15][lq * 8]);
    }
#pragma unroll
    for (int i = 0; i < 4; ++i)
#pragma unroll
      for (int j = 0; j < 4; ++j) {
        acc[i][j] = __builtin_amdgcn_mfma_f32_16x16x32_bf16(ah[i], bh[j], acc[i][j], 0, 0, 0);
        acc[i][j] = __builtin_amdgcn_mfma_f32_16x16x32_bf16(ah[i], bl[j], acc[i][j], 0, 0, 0);
        acc[i][j] = __builtin_amdgcn_mfma_f32_16x16x32_bf16(al[i], bh[j], acc[i][j], 0, 0, 0);
      }
    __syncthreads();
  }

  // epilogue: q = exp(acc/EPS), write Q0q, accumulate col sums (v == 1) into S
#pragma unroll
  for (int j = 0; j < 4; ++j) {
    int col = bn0 + wn0 + j * 16 + ln15;
    bool valid = col < K;
    float csum = 0.f;
#pragma unroll
    for (int i = 0; i < 4; ++i) {
      int rowb = bm0 + wm0 + i * 16 + lq * 4;
#pragma unroll
      for (int r = 0; r < 4; ++r) {
        float q = valid ? expf(acc[i][j][r] * INV_EPS) : 0.f;
        if (valid) Q0q[(size_t)(rowb + r) * K + col] = q;
        csum += q;
      }
    }
    csum += __shfl_xor(csum, 16, 64);
    csum += __shfl_xor(csum, 32, 64);
    if (lane < 16 && valid) atomicAdd(&S[col], csum);
  }
}

// -------- colsum over sample rows only, v == 1 (iteration 1 tail) --------
__global__ __launch_bounds__(256) void k_colsum_init(
    const float* __restrict__ outCrop, float* __restrict__ S) {
  int k4 = blockIdx.x * 256 + threadIdx.x;
  if (k4 >= K4) return;
  int n0 = blockIdx.y * CHUNK;
  float4 a = make_float4(0.f, 0.f, 0.f, 0.f);
  for (int nn = 0; nn < CHUNK; ++nn) {
    float4 o = reinterpret_cast<const float4*>(outCrop + (size_t)(n0 + nn) * K)[k4];
    a.x += expf(o.x * INV_EPS);
    a.y += expf(o.y * INV_EPS);
    a.z += expf(o.z * INV_EPS);
    a.w += expf(o.w * INV_EPS);
  }
  atomicAdd(&S[k4 * 4 + 0], a.x);
  atomicAdd(&S[k4 * 4 + 1], a.y);
  atomicAdd(&S[k4 * 4 + 2], a.z);
  atomicAdd(&S[k4 * 4 + 3], a.w);
}

// -------- full colsum with v --------
__global__ __launch_bounds__(256) void k_colsum(
    const float* __restrict__ Q0q, const float* __restrict__ outCrop,
    const float* __restrict__ v, float* __restrict__ S) {
  int k4 = blockIdx.x * 256 + threadIdx.x;
  if (k4 >= K4) return;
  int n0 = blockIdx.y * CHUNK;
  float4 a = make_float4(0.f, 0.f, 0.f, 0.f);
  for (int nn = 0; nn < CHUNK; ++nn) {
    int n = n0 + nn;
    float vn = v[n];
    float4 q;
    if (n < QL) {
      q = reinterpret_cast<const float4*>(Q0q + (size_t)n * K)[k4];
    } else {
      float4 o = reinterpret_cast<const float4*>(outCrop + (size_t)(n - QL) * K)[k4];
      q.x = expf(o.x * INV_EPS); q.y = expf(o.y * INV_EPS);
      q.z = expf(o.z * INV_EPS); q.w = expf(o.w * INV_EPS);
    }
    a.x += q.x * vn; a.y += q.y * vn; a.z += q.z * vn; a.w += q.w * vn;
  }
  atomicAdd(&S[k4 * 4 + 0], a.x);
  atomicAdd(&S[k4 * 4 + 1], a.y);
  atomicAdd(&S[k4 * 4 + 2], a.z);
  atomicAdd(&S[k4 * 4 + 3], a.w);
}

__global__ void k_update_u(const float* __restrict__ S, float* __restrict__ u) {
  int k = blockIdx.x * 256 + threadIdx.x;
  if (k < K) u[k] = 1.0f / ((float)K * S[k]);
}

// -------- v[n] = 1 / (NTOT * sum_k row[k]*u[k]) --------
__global__ __launch_bounds__(256) void k_rowpass(
    const float* __restrict__ Q0q, const float* __restrict__ outCrop,
    const float* __restrict__ u, float* __restrict__ v) {
  __shared__ float s4[4];
  int n = blockIdx.x;
  float acc = 0.f;
  if (n < QL) {
    const float4* row = reinterpret_cast<const float4*>(Q0q + (size_t)n * K);
    for (int k4 = threadIdx.x; k4 < K4; k4 += 256) {
      float4 q = row[k4];
      float4 uu = reinterpret_cast<const float4*>(u)[k4];
      acc += q.x * uu.x + q.y * uu.y + q.z * uu.z + q.w * uu.w;
    }
  } else {
    const float4* row = reinterpret_cast<const float4*>(outCrop + (size_t)(n - QL) * K);
    for (int k4 = threadIdx.x; k4 < K4; k4 += 256) {
      float4 o = row[k4];
      float4 uu = reinterpret_cast<const float4*>(u)[k4];
      acc += expf(o.x * INV_EPS) * uu.x + expf(o.y * INV_EPS) * uu.y +
             expf(o.z * INV_EPS) * uu.z + expf(o.w * INV_EPS) * uu.w;
    }
  }
  acc = wave_sum(acc);
  if ((threadIdx.x & 63) == 0) s4[threadIdx.x >> 6] = acc;
  __syncthreads();
  if (threadIdx.x == 0) v[n] = 1.0f / ((float)NTOT * (s4[0] + s4[1] + s4[2] + s4[3]));
}

// -------- per sample row: hard_q, neg_q, fused final-v, crop-1 cc term --------
__global__ __launch_bounds__(256) void k_stats(
    const float* __restrict__ outputAll, const float* __restrict__ u,
    int crop, int* __restrict__ hardq, int* __restrict__ negq, float* __restrict__ accum) {
  __shared__ float skey[K];                  // 12 KB
  __shared__ unsigned long long ml[256][8];  // 16 KB
  __shared__ unsigned long long sm4[4];
  __shared__ float red[4][4];
  const int tid = threadIdx.x;
  const int j = blockIdx.x;
  const float* orow = outputAll + (size_t)(crop * BS + j) * K;

  float svp = 0.f;
  for (int k4 = tid; k4 < K4; k4 += 256) {
    float4 o = reinterpret_cast<const float4*>(orow)[k4];
    float4 uu = reinterpret_cast<const float4*>(u)[k4];
    float4 kv;
    kv.x = expf(o.x * INV_EPS) * uu.x;
    kv.y = expf(o.y * INV_EPS) * uu.y;
    kv.z = expf(o.z * INV_EPS) * uu.z;
    kv.w = expf(o.w * INV_EPS) * uu.w;
    reinterpret_cast<float4*>(skey)[k4] = kv;
    svp += kv.x + kv.y + kv.z + kv.w;
  }
  svp = wave_sum(svp);
  if ((tid & 63) == 0) red[0][tid >> 6] = svp;
  __syncthreads();
  const float sv = red[0][0] + red[0][1] + red[0][2] + red[0][3];

  // argmax (first-occurrence): maximize (key, ~k)
  unsigned long long am = 0ull;
  for (int k = tid; k < K; k += 256) {
    unsigned long long p = ((unsigned long long)fmono(skey[k]) << 32) | (unsigned int)(~k);
    am = (p > am) ? p : am;
  }
  am = wave_maxu64(am);
  if ((tid & 63) == 0) sm4[tid >> 6] = am;

  // bottom-8 (stable ascending: minimize (key, k))
  unsigned long long best[8];
#pragma unroll
  for (int t = 0; t < 8; ++t) best[t] = ~0ull;
  for (int k = tid; k < K; k += 256) {
    unsigned long long p = ((unsigned long long)fmono(skey[k]) << 32) | (unsigned int)k;
    if (p < best[7]) {
      best[7] = p;
#pragma unroll
      for (int t = 7; t > 0; --t)
        if (best[t] < best[t - 1]) {
          unsigned long long tmp = best[t]; best[t] = best[t - 1]; best[t - 1] = tmp;
        }
    }
  }
#pragma unroll
  for (int t = 0; t < 8; ++t) ml[tid][t] = best[t];
  __syncthreads();
  for (int off = 128; off >= 1; off >>= 1) {
    if (tid < off) {
      unsigned long long a[8], b[8], o[8];
#pragma unroll
      for (int t = 0; t < 8; ++t) { a[t] = ml[tid][t]; b[t] = ml[tid + off][t]; }
      int ia = 0, ib = 0;
#pragma unroll
      for (int t = 0; t < 8; ++t) o[t] = (a[ia] <= b[ib]) ? a[ia++] : b[ib++];
#pragma unroll
      for (int t = 0; t < 8; ++t) ml[tid][t] = o[t];
    }
    __syncthreads();
  }
  if (tid == 0) {
    unsigned long long amx = sm4[0];
#pragma unroll
    for (int t = 1; t < 4; ++t) amx = (sm4[t] > amx) ? sm4[t] : amx;
    hardq[crop * BS + j] = (int)(~(unsigned int)(amx & 0xffffffffull));
#pragma unroll
    for (int r = 0; r < 6; ++r)
      negq[(size_t)(crop * BS + j) * 6 + r] = (int)(unsigned int)(ml[0][2 + r] & 0xffffffffull);
  }

  if (crop == 1) {
    const float* xrow = outputAll + (size_t)j * K;
    float mx = -3.4e38f;
    for (int k = tid; k < K; k += 256) mx = fmaxf(mx, xrow[k]);
    mx = wave_max(mx);
    if ((tid & 63) == 0) red[1][tid >> 6] = mx;
    __syncthreads();
    mx = fmaxf(fmaxf(red[1][0], red[1][1]), fmaxf(red[1][2], red[1][3]));
    float se = 0.f, sk = 0.f, skx = 0.f;
    for (int k4 = tid; k4 < K4; k4 += 256) {
      float4 x = reinterpret_cast<const float4*>(xrow)[k4];
      se += expf((x.x - mx) / TEMP) + expf((x.y - mx) / TEMP) +
            expf((x.z - mx) / TEMP) + expf((x.w - mx) / TEMP);
      float4 kv = reinterpret_cast<const float4*>(skey)[k4];
      sk  += kv.x + kv.y + kv.z + kv.w;
      skx += kv.x * x.x + kv.y * x.y + kv.z * x.z + kv.w * x.w;
    }
    se = wave_sum(se); sk = wave_sum(sk); skx = wave_sum(skx);
    if ((tid & 63) == 0) { int w = tid >> 6; red[1][w] = se; red[2][w] = sk; red[3][w] = skx; }
    __syncthreads();
    if (tid == 0) {
      float SE  = red[1][0] + red[1][1] + red[1][2] + red[1][3];
      float SK  = red[2][0] + red[2][1] + red[2][2] + red[2][3];
      float SKX = red[3][0] + red[3][1] + red[3][2] + red[3][3];
      float bv  = 1.0f / sv;               // == NTOT * v_final
      float sq  = bv * SK;
      float sqx = bv * SKX / TEMP;
      float lse = mx / TEMP + logf(SE);
      atomicAdd(&accum[2], sqx - lse * sq);
    }
  }
}

__global__ __launch_bounds__(256) void k_normalize(
    const float* __restrict__ emb, float* __restrict__ outc) {
  __shared__ float s4[4];
  __shared__ float nrm;
  int r = blockIdx.x;
  int src = (r < BS) ? (BS + r) : (r - BS);
  float z = emb[(size_t)src * DIM + threadIdx.x] / TEMP;
  float ss = wave_sum(z * z);
  if ((threadIdx.x & 63) == 0) s4[threadIdx.x >> 6] = ss;
  __syncthreads();
  if (threadIdx.x == 0) nrm = sqrtf(s4[0] + s4[1] + s4[2] + s4[3]);
  __syncthreads();
  outc[(size_t)r * DIM + threadIdx.x] = z / nrm;
}

__global__ __launch_bounds__(256) void k_pos(
    const float* __restrict__ outc, float* __restrict__ accum) {
  int wid = threadIdx.x >> 6, lane = threadIdx.x & 63;
  int j = blockIdx.x * 4 + wid;
  const float4 a = reinterpret_cast<const float4*>(outc + (size_t)j * DIM)[lane];
  const float4 b = reinterpret_cast<const float4*>(outc + (size_t)(BS + j) * DIM)[lane];
  float d = a.x * b.x + a.y * b.y + a.z * b.z + a.w * b.w;
  d = wave_sum(d);
  if (lane == 0) atomicAdd(&accum[1], d);
}

__global__ __launch_bounds__(256) void k_denom(
    const float* __restrict__ outc, const int* __restrict__ hardq,
    const int* __restrict__ negq, float* __restrict__ accum) {
  __shared__ int shq[N2];
  __shared__ float4 srow[64];
  __shared__ float s4[4];
  const int i = blockIdx.x;
  const int tid = threadIdx.x;
  for (int t = tid; t < N2; t += 256) shq[t] = hardq[t];
  if (tid < 64) srow[tid] = reinterpret_cast<const float4*>(outc + (size_t)i * DIM)[tid];
  int q0 = negq[i * 6 + 0], q1 = negq[i * 6 + 1], q2 = negq[i * 6 + 2],
      q3 = negq[i * 6 + 3], q4 = negq[i * 6 + 4], q5 = negq[i * 6 + 5];
  __syncthreads();
  float acc = 0.f;
  for (int jj = tid; jj < N2; jj += 256) {
    if (jj == i) continue;
    int h = shq[jj];
    if (h == q0 || h == q1 || h == q2 || h == q3 || h == q4 || h == q5) {
      const float4* rj = reinterpret_cast<const float4*>(outc + (size_t)jj * DIM);
      float ds = 0.f;
#pragma unroll 8
      for (int d4 = 0; d4 < 64; ++d4) {
        float4 a = srow[d4]; float4 b = rj[d4];
        ds += a.x * b.x + a.y * b.y + a.z * b.z + a.w * b.w;
      }
      acc += expf(ds / TEMP);
    }
  }
  acc = wave_sum(acc);
  __syncthreads();
  if ((tid & 63) == 0) s4[tid >> 6] = acc;
  __syncthreads();
  if (tid == 0) atomicAdd(&accum[0], s4[0] + s4[1] + s4[2] + s4[3]);
}

__global__ void k_final(const float* __restrict__ accum, float* __restrict__ out) {
  float denom  = accum[0];
  float possum = accum[1];
  float ccsum  = accum[2];
  float contrast = logf(denom) - possum / ((float)BS * TEMP);
  float cc_loss  = -ccsum / (float)BS;
  out[0] = contrast + 6.0f * cc_loss;
}

}  // namespace

extern "C" void kernel_launch(void* const* d_in, const int* in_sizes, int n_in,
                              void* d_out, int out_size, void* d_ws, size_t ws_size,
                              hipStream_t stream) {
  const float* queue  = (const float*)d_in[3];  // [2][QL][DIM]
  const float* proto  = (const float*)d_in[4];  // [K][DIM]
  const float* output = (const float*)d_in[5];  // [2*BS][K]
  const float* emb    = (const float*)d_in[6];  // [2*BS][DIM]
  float* ws = (float*)d_ws;
  float* Q0q   = ws + OFF_Q0Q;
  float* u     = ws + OFF_U;
  float* S     = ws + OFF_S;
  float* v     = ws + OFF_V;
  float* accum = ws + OFF_ACC;
  int* hardq = (int*)(ws + OFF_HQ);
  int* negq  = (int*)(ws + OFF_NQ);
  ushort* cvt_hi = (ushort*)(ws + OFF_CVT_HI);
  ushort* cvt_lo = (ushort*)(ws + OFF_CVT_LO);
  float* outc  = ws + OFF_OUTC;
  float* out = (float*)d_out;

  hipMemsetAsync(accum, 0, 8 * sizeof(float), stream);

  // split-bf16 conversion: queue (both crops) then proto
  {
    int n4q = 2 * QL * DIM / 4;
    k_convert<<<(n4q + 255) / 256, 256, 0, stream>>>(queue, cvt_hi, cvt_lo, n4q);
    int n4p = K * DIM / 4;
    k_convert<<<(n4p + 255) / 256, 256, 0, stream>>>(
        proto, cvt_hi + (size_t)2 * QL * DIM, cvt_lo + (size_t)2 * QL * DIM, n4p);
  }

  for (int crop = 0; crop < 2; ++crop) {
    const float* ocrop = output + (size_t)crop * BS * K;
    const ushort* Ahi = cvt_hi + (size_t)crop * QL * DIM;
    const ushort* Alo = cvt_lo + (size_t)crop * QL * DIM;
    const ushort* Bhi = cvt_hi + (size_t)2 * QL * DIM;
    const ushort* Blo = cvt_lo + (size_t)2 * QL * DIM;

    // iteration 1 colsum fused into GEMM epilogue (v == 1)
    hipMemsetAsync(S, 0, K * sizeof(float), stream);
    k_gemm_split<<<dim3((K + 127) / 128, QL / 128), 256, 0, stream>>>(
        Ahi, Alo, Bhi, Blo, Q0q, S);
    k_colsum_init<<<dim3((K4 + 255) / 256, BS / CHUNK), 256, 0, stream>>>(ocrop, S);
    k_update_u<<<(K + 255) / 256, 256, 0, stream>>>(S, u);
    k_rowpass<<<NTOT, 256, 0, stream>>>(Q0q, ocrop, u, v);     // it1 -> v1

    hipMemsetAsync(S, 0, K * sizeof(float), stream);
    k_colsum<<<dim3((K4 + 255) / 256, NTOT / CHUNK), 256, 0, stream>>>(Q0q, ocrop, v, S);
    k_update_u<<<(K + 255) / 256, 256, 0, stream>>>(S, u);     // u2
    k_rowpass<<<NTOT, 256, 0, stream>>>(Q0q, ocrop, u, v);     // it2 -> v2

    hipMemsetAsync(S, 0, K * sizeof(float), stream);
    k_colsum<<<dim3((K4 + 255) / 256, NTOT / CHUNK), 256, 0, stream>>>(Q0q, ocrop, v, S);
    k_update_u<<<(K + 255) / 256, 256, 0, stream>>>(S, u);     // u3

    // it3 rowpass needed only for sample rows -> fused into stats
    k_stats<<<BS, 256, 0, stream>>>(output, u, crop, hardq, negq, accum);
  }

  k_normalize<<<N2, 256, 0, stream>>>(emb, outc);
  k_pos<<<BS / 4, 256, 0, stream>>>(outc, accum);
  k_denom<<<N2, 256, 0, stream>>>(outc, hardq, negq, accum);
  k_final<<<1, 1, 0, stream>>>(accum, out);
}